// Round 4
// baseline (65.145 us; speedup 1.0000x reference)
//
#include <hip/hip_runtime.h>

#define N_ROWS   1024
#define D_DIM    128
#define C_CLS    50000
#define C_PAD    50048
#define NCT      391        // 50048 / 128
#define S_SCALE  30.0f
#define M_MARGIN 0.35f

typedef short s8v __attribute__((ext_vector_type(8)));   // 8 x bf16 bits (4 VGPRs)
typedef float f4v __attribute__((ext_vector_type(4)));

__device__ inline unsigned short f2bf(float f) {
    unsigned u = __float_as_uint(f);
    u += 0x7FFF + ((u >> 16) & 1);      // round-to-nearest-even (inputs are finite)
    return (unsigned short)(u >> 16);
}
__device__ inline float bf2f(unsigned short h) {
    return __uint_as_float(((unsigned)h) << 16);
}

// ---------------------------------------------------------------------------
// Normalize rows of a [rows][128] fp32 matrix -> bf16. One wave per row.
// Rows >= validRows are written as zeros (padding for the GEMM col tail).
// ---------------------------------------------------------------------------
__global__ void norm_rows_kernel(const float* __restrict__ in,
                                 unsigned short* __restrict__ out,
                                 int totalRows, int validRows) {
    int wid = threadIdx.x >> 6, lane = threadIdx.x & 63;
    int r = blockIdx.x * 4 + wid;
    if (r >= totalRows) return;
    float2 v = make_float2(0.f, 0.f);
    if (r < validRows) v = ((const float2*)in)[(size_t)r * 64 + lane];
    float ss = v.x * v.x + v.y * v.y;
    #pragma unroll
    for (int s = 1; s < 64; s <<= 1) ss += __shfl_xor(ss, s, 64);
    float inv = 0.f;
    if (r < validRows) inv = 1.0f / fmaxf(sqrtf(ss), 1e-8f);
    ((ushort2*)out)[(size_t)r * 64 + lane] = make_ushort2(f2bf(v.x * inv), f2bf(v.y * inv));
}

// ---------------------------------------------------------------------------
// 128x128 output tile, K=128 (whole K, single shot). 4 waves in 2x2.
// A = fhat rows (rt*128..), B^T = what rows (ct*128..) -- both row-major [*][128],
// so both tiles are CONTIGUOUS 32KB chunks; staged via global_load_lds width=16
// with XOR swizzle done on the GLOBAL source (LDS dest stays linear, rule #21).
// Epilogue: masked exp(30*cos), 16-lane shuffle row-reduce, per-block partial
// row sums -> part[row*NCT + ct]. No atomics (determinism).
// ---------------------------------------------------------------------------
__global__ void gemm_exp_kernel(const short* __restrict__ fhat,
                                const short* __restrict__ what,
                                float* __restrict__ part) {
    __shared__ __align__(16) unsigned char smem[65536];   // A: [0,32K), B: [32K,64K)
    const int ct  = blockIdx.x;
    const int rt  = blockIdx.y;
    const int tid = threadIdx.x;
    const int wid = tid >> 6;
    const int lane = tid & 63;

    const char* aSrc = (const char*)fhat + (size_t)rt * 32768;
    const char* bSrc = (const char*)what + (size_t)ct * 32768;

    // stage: each wave moves 8KB of A and 8KB of B, 1KB per instruction
    #pragma unroll
    for (int i = 0; i < 8; i++) {
        int o = wid * 8192 + i * 1024 + lane * 16;
        int g = o ^ (((o >> 8) & 7) << 4);        // involution: source pre-swizzle
        __builtin_amdgcn_global_load_lds(
            (const __attribute__((address_space(1))) void*)(aSrc + g),
            (__attribute__((address_space(3))) void*)(smem + o), 16, 0, 0);
        __builtin_amdgcn_global_load_lds(
            (const __attribute__((address_space(1))) void*)(bSrc + g),
            (__attribute__((address_space(3))) void*)(smem + 32768 + o), 16, 0, 0);
    }
    __syncthreads();

    const int wr = (wid >> 1) * 64;   // wave row offset in tile
    const int wc = (wid & 1) * 64;    // wave col offset in tile
    const int lrow = lane & 15;
    const int kgrp = lane >> 4;

    f4v zero = {0.f, 0.f, 0.f, 0.f};
    f4v acc[4][4];
    #pragma unroll
    for (int m = 0; m < 4; m++)
        #pragma unroll
        for (int n = 0; n < 4; n++) acc[m][n] = zero;

    #pragma unroll
    for (int kk = 0; kk < 4; kk++) {
        const int kb2 = kk * 64 + kgrp * 16;     // byte offset of this lane's k8 in a row
        s8v afr[4], bfr[4];
        #pragma unroll
        for (int m = 0; m < 4; m++) {
            int row = wr + m * 16 + lrow;
            int b = (row * 256 + kb2) ^ ((row & 7) << 4);
            afr[m] = *(const s8v*)(smem + b);
        }
        #pragma unroll
        for (int n = 0; n < 4; n++) {
            int row = wc + n * 16 + lrow;        // B^T row = output col
            int b = (row * 256 + kb2) ^ ((row & 7) << 4);
            bfr[n] = *(const s8v*)(smem + 32768 + b);
        }
        #pragma unroll
        for (int m = 0; m < 4; m++)
            #pragma unroll
            for (int n = 0; n < 4; n++)
                acc[m][n] = __builtin_amdgcn_mfma_f32_16x16x32_bf16(afr[m], bfr[n], acc[m][n], 0, 0, 0);
    }

    __syncthreads();                      // everyone done reading A/B before smem reuse
    float* srow = (float*)smem;           // [2][128] partial row sums

    const int cbase = ct * 128 + wc;
    #pragma unroll
    for (int m = 0; m < 4; m++) {
        #pragma unroll
        for (int j = 0; j < 4; j++) {
            float v = 0.f;
            #pragma unroll
            for (int n = 0; n < 4; n++) {
                int gc = cbase + n * 16 + lrow;
                float e = __expf(S_SCALE * acc[m][n][j]);
                v += (gc < C_CLS) ? e : 0.f;
            }
            #pragma unroll
            for (int s = 1; s < 16; s <<= 1) v += __shfl_xor(v, s, 64);
            if (lrow == 0) {
                int localrow = wr + m * 16 + kgrp * 4 + j;   // C/D map: row=(lane>>4)*4+j
                srow[(wid & 1) * 128 + localrow] = v;
            }
        }
    }
    __syncthreads();
    if (tid < 128) {
        float s = srow[tid] + srow[128 + tid];
        part[(size_t)(rt * 128 + tid) * NCT + ct] = s;
    }
}

// ---------------------------------------------------------------------------
// One wave per row: S_n = sum of partials; cos_y (fp32 dot of the SAME bf16
// normalized vectors -> consistent with GEMM to ~1e-6 relative); center loss.
// rowval[n] = (lse_n - t_n)/N + 0.005 * ||f_n - w_y||^2
// ---------------------------------------------------------------------------
__global__ void finalize_rows_kernel(const float* __restrict__ part,
                                     const unsigned short* __restrict__ fhat,
                                     const unsigned short* __restrict__ what,
                                     const float* __restrict__ feature,
                                     const float* __restrict__ weight,
                                     const int* __restrict__ label,
                                     float* __restrict__ rowval) {
    int wid = threadIdx.x >> 6, lane = threadIdx.x & 63;
    int n = blockIdx.x * 4 + wid;
    int y = label[n];

    float S = 0.f;
    const float* p = part + (size_t)n * NCT;
    for (int c = lane; c < NCT; c += 64) S += p[c];

    float2 f2 = ((const float2*)feature)[(size_t)n * 64 + lane];
    float2 w2 = ((const float2*)weight)[(size_t)y * 64 + lane];
    float dx = f2.x - w2.x, dy = f2.y - w2.y;
    float cl = dx * dx + dy * dy;

    ushort2 fh = ((const ushort2*)fhat)[(size_t)n * 64 + lane];
    ushort2 wh = ((const ushort2*)what)[(size_t)y * 64 + lane];
    float cy = bf2f(fh.x) * bf2f(wh.x) + bf2f(fh.y) * bf2f(wh.y);

    #pragma unroll
    for (int s = 1; s < 64; s <<= 1) {
        S  += __shfl_xor(S, s, 64);
        cl += __shfl_xor(cl, s, 64);
        cy += __shfl_xor(cy, s, 64);
    }
    if (lane == 0) {
        float t  = S_SCALE * (cy - M_MARGIN);
        float Sp = S - __expf(S_SCALE * cy) + __expf(t);
        rowval[n] = (logf(Sp) - t) * (1.0f / (float)N_ROWS) + 0.005f * cl;
    }
}

__global__ void reduce_final_kernel(const float* __restrict__ rowval, float* __restrict__ out) {
    __shared__ float sbuf[4];
    int t = threadIdx.x;
    float v = rowval[t] + rowval[t + 256] + rowval[t + 512] + rowval[t + 768];
    #pragma unroll
    for (int s = 1; s < 64; s <<= 1) v += __shfl_xor(v, s, 64);
    if ((t & 63) == 0) sbuf[t >> 6] = v;
    __syncthreads();
    if (t == 0) out[0] = sbuf[0] + sbuf[1] + sbuf[2] + sbuf[3];
}

// ---------------------------------------------------------------------------
extern "C" void kernel_launch(void* const* d_in, const int* in_sizes, int n_in,
                              void* d_out, int out_size, void* d_ws, size_t ws_size,
                              hipStream_t stream) {
    const float* feature = (const float*)d_in[0];
    const float* weight  = (const float*)d_in[1];
    const int*   label   = (const int*)d_in[2];

    // Workspace layout (bytes):
    //   what   [0,           12812288)  : 50048*128*2
    //   fhat   [12812288,    13074432)  : 1024*128*2
    //   part   [13074432,    14675968)  : 1024*391*4
    //   rowval [14675968,    14680064)  : 1024*4
    const size_t WS_NEEDED = 14680064;
    if (ws_size < WS_NEEDED) return;   // defensive: visible failure, not OOB writes

    char* ws = (char*)d_ws;
    unsigned short* what = (unsigned short*)ws;
    unsigned short* fhat = (unsigned short*)(ws + 12812288);
    float*          part = (float*)(ws + 13074432);
    float*        rowval = (float*)(ws + 14675968);

    norm_rows_kernel<<<dim3(C_PAD / 4), 256, 0, stream>>>(weight, what, C_PAD, C_CLS);
    norm_rows_kernel<<<dim3(N_ROWS / 4), 256, 0, stream>>>(feature, fhat, N_ROWS, N_ROWS);
    gemm_exp_kernel<<<dim3(NCT, 8), 256, 0, stream>>>((const short*)fhat, (const short*)what, part);
    finalize_rows_kernel<<<dim3(N_ROWS / 4), 256, 0, stream>>>(part, fhat, what, feature, weight,
                                                               label, rowval);
    reduce_final_kernel<<<1, 256, 0, stream>>>(rowval, (float*)d_out);
}

// Round 5
// 39.603 us; speedup vs baseline: 1.6450x; 1.6450x over previous
//
#include <hip/hip_runtime.h>

#define N_ROWS   1024
#define D_DIM    128
#define C_CLS    50000
#define C_PAD    50048
#define NCT      391        // 50048 / 128 column tiles
#define NG       64         // ct groups (gemm grid.x); 391 = 6*64 + 7
#define S_SCALE  30.0f
#define M_MARGIN 0.35f

typedef short s8v __attribute__((ext_vector_type(8)));   // 8 x bf16 bits (4 VGPRs)
typedef float f4v __attribute__((ext_vector_type(4)));

__device__ inline unsigned short f2bf(float f) {
    unsigned u = __float_as_uint(f);
    u += 0x7FFF + ((u >> 16) & 1);      // round-to-nearest-even (inputs are finite)
    return (unsigned short)(u >> 16);
}
__device__ inline float bf2f(unsigned short h) {
    return __uint_as_float(((unsigned)h) << 16);
}
__device__ inline void load_lds16(const char* src, unsigned char* lds) {
    __builtin_amdgcn_global_load_lds(
        (const __attribute__((address_space(1))) void*)src,
        (__attribute__((address_space(3))) void*)lds, 16, 0, 0);
}

// ---------------------------------------------------------------------------
// Fused row-normalize: rows [0,C_PAD) = weight -> what (rows >= C_CLS zeroed),
// rows [C_PAD, C_PAD+N_ROWS) = feature -> fhat. One wave per row.
// ---------------------------------------------------------------------------
__global__ void norm_rows_fused(const float* __restrict__ weight,
                                const float* __restrict__ feature,
                                unsigned short* __restrict__ what,
                                unsigned short* __restrict__ fhat) {
    int wid = threadIdx.x >> 6, lane = threadIdx.x & 63;
    int r = blockIdx.x * 4 + wid;
    const float* src;
    unsigned short* dst;
    int srcRow, valid;
    if (r < C_PAD) {                      // wave-uniform branch
        src = weight; dst = what; srcRow = r; valid = (r < C_CLS);
    } else {
        src = feature; dst = fhat; srcRow = r - C_PAD; valid = 1;
    }
    float2 v = make_float2(0.f, 0.f);
    if (valid) v = ((const float2*)src)[(size_t)srcRow * 64 + lane];
    float ss = v.x * v.x + v.y * v.y;
    #pragma unroll
    for (int s = 1; s < 64; s <<= 1) ss += __shfl_xor(ss, s, 64);
    float inv = valid ? 1.0f / fmaxf(sqrtf(ss), 1e-8f) : 0.f;
    int dstRow = (r < C_PAD) ? r : srcRow;
    ((ushort2*)dst)[(size_t)dstRow * 64 + lane] =
        make_ushort2(f2bf(v.x * inv), f2bf(v.y * inv));
}

// ---------------------------------------------------------------------------
// ct-loop GEMM+exp. Block (g, rt): A = fhat rows [rt*128,+128) held in
// registers (loaded once via LDS bounce); B tiles ct = g + 64*t streamed
// through a 2x32KB double buffer (global_load_lds w16, XOR swizzle on the
// GLOBAL source per rule #21, linear LDS dest). 2-phase pipeline: issue
// next-tile stage BEFORE ds_read+MFMA, one vmcnt(0)+barrier per tile (T3
// minimal recipe). exp(30*cos) accumulates into per-lane esum[m][j] across
// tiles; ONE 16-lane shuffle reduce + part2[row][g] write per block.
// grid linear id = g + 64*rt -> all 8 rt sharing B tiles land on one XCD.
// ---------------------------------------------------------------------------
__global__ __launch_bounds__(256, 2)
void gemm_exp_kernel(const short* __restrict__ fhat,
                     const short* __restrict__ what,
                     float* __restrict__ part2) {
    __shared__ __align__(16) unsigned char smem[65536];   // buf0 | buf1 (32KB each)
    const int g   = blockIdx.x;           // ct group, 0..63
    const int rt  = blockIdx.y;           // row tile, 0..7
    const int tid = threadIdx.x;
    const int wid = tid >> 6;
    const int lane = tid & 63;
    const int nt = (g < 7) ? 7 : 6;       // tiles in this group

    const char* aSrc  = (const char*)fhat + (size_t)rt * 32768;
    const char* bBase = (const char*)what;

    // prologue: A -> buf0, B(ct=g) -> buf1
    #pragma unroll
    for (int i = 0; i < 8; i++) {
        int o = wid * 8192 + i * 1024 + lane * 16;
        int s = o ^ (((o >> 8) & 7) << 4);      // source pre-swizzle (involution)
        load_lds16(aSrc + s, smem + o);
        load_lds16(bBase + (size_t)g * 32768 + s, smem + 32768 + o);
    }
    __syncthreads();

    const int wr = (wid >> 1) * 64;       // wave row offset
    const int wc = (wid & 1) * 64;        // wave col offset
    const int lrow = lane & 15;
    const int kgrp = lane >> 4;

    // A panel -> registers (16 s8v = 64 VGPR), swizzled ds_read
    s8v afr[4][4];
    #pragma unroll
    for (int kk = 0; kk < 4; kk++)
        #pragma unroll
        for (int m = 0; m < 4; m++) {
            int row = wr + m * 16 + lrow;
            int b = (row * 256 + kk * 64 + kgrp * 16) ^ ((row & 7) << 4);
            afr[kk][m] = *(const s8v*)(smem + b);
        }
    __syncthreads();                      // all A reads done -> buf0 reusable

    float esum[4][4];
    #pragma unroll
    for (int m = 0; m < 4; m++)
        #pragma unroll
        for (int j = 0; j < 4; j++) esum[m][j] = 0.f;

    int cur = 1;
    for (int t = 0; t < nt; ++t) {
        const int ct = g + 64 * t;
        if (t + 1 < nt) {                 // issue next-tile stage first
            const char* src = bBase + (size_t)(ct + 64) * 32768;
            unsigned char* dstb = smem + (cur ^ 1) * 32768;
            #pragma unroll
            for (int i = 0; i < 8; i++) {
                int o = wid * 8192 + i * 1024 + lane * 16;
                int s = o ^ (((o >> 8) & 7) << 4);
                load_lds16(src + s, dstb + o);
            }
        }

        const unsigned char* bb = smem + cur * 32768;
        f4v acc[4][4];
        f4v zero = {0.f, 0.f, 0.f, 0.f};
        #pragma unroll
        for (int m = 0; m < 4; m++)
            #pragma unroll
            for (int n = 0; n < 4; n++) acc[m][n] = zero;

        #pragma unroll
        for (int kk = 0; kk < 4; kk++) {
            s8v bfr[4];
            #pragma unroll
            for (int n = 0; n < 4; n++) {
                int row = wc + n * 16 + lrow;
                int b = (row * 256 + kk * 64 + kgrp * 16) ^ ((row & 7) << 4);
                bfr[n] = *(const s8v*)(bb + b);
            }
            #pragma unroll
            for (int m = 0; m < 4; m++)
                #pragma unroll
                for (int n = 0; n < 4; n++)
                    acc[m][n] = __builtin_amdgcn_mfma_f32_16x16x32_bf16(
                        afr[kk][m], bfr[n], acc[m][n], 0, 0, 0);
        }

        if (ct != NCT - 1) {              // fast path: all 128 cols valid
            #pragma unroll
            for (int m = 0; m < 4; m++)
                #pragma unroll
                for (int n = 0; n < 4; n++)
                    #pragma unroll
                    for (int j = 0; j < 4; j++)
                        esum[m][j] += __expf(S_SCALE * acc[m][n][j]);
        } else {                          // tail tile: mask padded cols
            int cbase = ct * 128 + wc;
            #pragma unroll
            for (int m = 0; m < 4; m++)
                #pragma unroll
                for (int n = 0; n < 4; n++) {
                    int gc = cbase + n * 16 + lrow;
                    #pragma unroll
                    for (int j = 0; j < 4; j++)
                        if (gc < C_CLS) esum[m][j] += __expf(S_SCALE * acc[m][n][j]);
                }
        }
        __syncthreads();                  // drains stage (vmcnt) + all bb reads done
        cur ^= 1;
    }

    // block epilogue: 16-lane reduce over lrow, funnel via LDS, one write/row
    float* srow = (float*)smem;           // [2][128]
    #pragma unroll
    for (int m = 0; m < 4; m++)
        #pragma unroll
        for (int j = 0; j < 4; j++) {
            float v = esum[m][j];
            v += __shfl_xor(v, 1, 64);
            v += __shfl_xor(v, 2, 64);
            v += __shfl_xor(v, 4, 64);
            v += __shfl_xor(v, 8, 64);
            if (lrow == 0)
                srow[(wid & 1) * 128 + wr + m * 16 + kgrp * 4 + j] = v;
        }
    __syncthreads();
    if (tid < 128)
        part2[(size_t)(rt * 128 + tid) * NG + g] = srow[tid] + srow[128 + tid];
}

// ---------------------------------------------------------------------------
// One wave per row: S_n = sum of 64 group partials (one per lane); cos_y via
// fp32 dot of the SAME bf16 normalized vectors; center loss on fp32 inputs.
// rowval[n] = (lse_n - t_n)/N + 0.005 * ||f_n - w_y||^2
// ---------------------------------------------------------------------------
__global__ void finalize_rows_kernel(const float* __restrict__ part2,
                                     const unsigned short* __restrict__ fhat,
                                     const unsigned short* __restrict__ what,
                                     const float* __restrict__ feature,
                                     const float* __restrict__ weight,
                                     const int* __restrict__ label,
                                     float* __restrict__ rowval) {
    int wid = threadIdx.x >> 6, lane = threadIdx.x & 63;
    int n = blockIdx.x * 4 + wid;
    int y = label[n];

    float S = part2[(size_t)n * NG + lane];   // one group partial per lane

    float2 f2 = ((const float2*)feature)[(size_t)n * 64 + lane];
    float2 w2 = ((const float2*)weight)[(size_t)y * 64 + lane];
    float dx = f2.x - w2.x, dy = f2.y - w2.y;
    float cl = dx * dx + dy * dy;

    ushort2 fh = ((const ushort2*)fhat)[(size_t)n * 64 + lane];
    ushort2 wh = ((const ushort2*)what)[(size_t)y * 64 + lane];
    float cy = bf2f(fh.x) * bf2f(wh.x) + bf2f(fh.y) * bf2f(wh.y);

    #pragma unroll
    for (int s = 1; s < 64; s <<= 1) {
        S  += __shfl_xor(S, s, 64);
        cl += __shfl_xor(cl, s, 64);
        cy += __shfl_xor(cy, s, 64);
    }
    if (lane == 0) {
        float t  = S_SCALE * (cy - M_MARGIN);
        float Sp = S - __expf(S_SCALE * cy) + __expf(t);
        rowval[n] = (logf(Sp) - t) * (1.0f / (float)N_ROWS) + 0.005f * cl;
    }
}

__global__ void reduce_final_kernel(const float* __restrict__ rowval, float* __restrict__ out) {
    __shared__ float sbuf[4];
    int t = threadIdx.x;
    float v = rowval[t] + rowval[t + 256] + rowval[t + 512] + rowval[t + 768];
    #pragma unroll
    for (int s = 1; s < 64; s <<= 1) v += __shfl_xor(v, s, 64);
    if ((t & 63) == 0) sbuf[t >> 6] = v;
    __syncthreads();
    if (t == 0) out[0] = sbuf[0] + sbuf[1] + sbuf[2] + sbuf[3];
}

// ---------------------------------------------------------------------------
extern "C" void kernel_launch(void* const* d_in, const int* in_sizes, int n_in,
                              void* d_out, int out_size, void* d_ws, size_t ws_size,
                              hipStream_t stream) {
    const float* feature = (const float*)d_in[0];
    const float* weight  = (const float*)d_in[1];
    const int*   label   = (const int*)d_in[2];

    // Workspace layout (bytes):
    //   what   [0,        12812288)  : 50048*128*2
    //   fhat   [12812288, 13074432)  : 1024*128*2
    //   part2  [13074432, 13336576)  : 1024*64*4
    //   rowval [13336576, 13340672)  : 1024*4
    const size_t WS_NEEDED = 13340672;
    if (ws_size < WS_NEEDED) return;   // defensive: visible failure, not OOB writes

    char* ws = (char*)d_ws;
    unsigned short* what = (unsigned short*)ws;
    unsigned short* fhat = (unsigned short*)(ws + 12812288);
    float*         part2 = (float*)(ws + 13074432);
    float*        rowval = (float*)(ws + 13336576);

    norm_rows_fused<<<dim3((C_PAD + N_ROWS) / 4), 256, 0, stream>>>(weight, feature, what, fhat);
    gemm_exp_kernel<<<dim3(NG, 8), 256, 0, stream>>>((const short*)fhat, (const short*)what, part2);
    finalize_rows_kernel<<<dim3(N_ROWS / 4), 256, 0, stream>>>(part2, fhat, what, feature, weight,
                                                               label, rowval);
    reduce_final_kernel<<<1, 256, 0, stream>>>(rowval, (float*)d_out);
}

// Round 6
// 37.806 us; speedup vs baseline: 1.7232x; 1.0475x over previous
//
#include <hip/hip_runtime.h>

#define N_ROWS   1024
#define D_DIM    128
#define C_CLS    50000
#define C_PAD    50048
#define NCT64    782        // 50048/64 column tiles (64 cols each)
#define NG       128        // ct groups; 782 = 6*128 + 14
#define S_SCALE  30.0f
#define M_MARGIN 0.35f
#define EXP2_SCALE 43.2808512266689f   // 30 * log2(e)

typedef short s8v __attribute__((ext_vector_type(8)));   // 8 x bf16 bits (4 VGPRs)
typedef float f4v __attribute__((ext_vector_type(4)));

__device__ inline unsigned short f2bf(float f) {
    unsigned u = __float_as_uint(f);
    u += 0x7FFF + ((u >> 16) & 1);      // round-to-nearest-even (inputs are finite)
    return (unsigned short)(u >> 16);
}
__device__ inline float bf2f(unsigned short h) {
    return __uint_as_float(((unsigned)h) << 16);
}
__device__ inline void load_lds16(const char* src, unsigned char* lds) {
    __builtin_amdgcn_global_load_lds(
        (const __attribute__((address_space(1))) void*)src,
        (__attribute__((address_space(3))) void*)lds, 16, 0, 0);
}

// ---------------------------------------------------------------------------
// Fused row-normalize: rows [0,C_PAD) = weight -> what (rows >= C_CLS zeroed),
// rows [C_PAD, C_PAD+N_ROWS) = feature -> fhat. One wave per row.
// ---------------------------------------------------------------------------
__global__ void norm_rows_fused(const float* __restrict__ weight,
                                const float* __restrict__ feature,
                                unsigned short* __restrict__ what,
                                unsigned short* __restrict__ fhat) {
    int wid = threadIdx.x >> 6, lane = threadIdx.x & 63;
    int r = blockIdx.x * 4 + wid;
    const float* src;
    unsigned short* dst;
    int srcRow, valid;
    if (r < C_PAD) {                      // wave-uniform branch
        src = weight; dst = what; srcRow = r; valid = (r < C_CLS);
    } else {
        src = feature; dst = fhat; srcRow = r - C_PAD; valid = 1;
    }
    float2 v = make_float2(0.f, 0.f);
    if (valid) v = ((const float2*)src)[(size_t)srcRow * 64 + lane];
    float ss = v.x * v.x + v.y * v.y;
    #pragma unroll
    for (int s = 1; s < 64; s <<= 1) ss += __shfl_xor(ss, s, 64);
    float inv = valid ? 1.0f / fmaxf(sqrtf(ss), 1e-8f) : 0.f;
    ((ushort2*)dst)[(size_t)srcRow * 64 + lane] =
        make_ushort2(f2bf(v.x * inv), f2bf(v.y * inv));
}

// ---------------------------------------------------------------------------
// ct-loop GEMM+exp, occupancy-tuned. Block (g, rt): output 128 rows x 64 cols
// per tile, tiles ct = g + 128*t. A panel (128x128, 32KB) staged once through
// LDS into registers; B tiles (64x128 = 16KB) double-buffered in 32KB LDS.
// 2-phase pipeline: issue next-tile global_load_lds BEFORE ds_read+MFMA, one
// vmcnt-drain barrier per tile. XOR swizzle on the GLOBAL source (rule #21),
// linear LDS dest, swizzled ds_read. Wave layout 4x1 (wave owns 32 rows, all
// 64 cols) -> epilogue is shuffle-reduce + direct global write, no LDS pass.
// exp2-accumulate into esum across tiles; one write per row per block.
// Grid linear id = g + 128*rt -> all 8 rt sharing a B tile on one XCD.
// ---------------------------------------------------------------------------
__global__ __launch_bounds__(256, 4)
void gemm_exp_kernel(const short* __restrict__ fhat,
                     const short* __restrict__ what,
                     float* __restrict__ part2) {
    __shared__ __align__(16) unsigned char smem[32768];   // A prologue OR 2x16KB B dbuf
    const int g   = blockIdx.x;           // ct group, 0..127
    const int rt  = blockIdx.y;           // row tile, 0..7
    const int tid = threadIdx.x;
    const int wid = tid >> 6;
    const int lane = tid & 63;
    const int nt = (g < 14) ? 7 : 6;      // tiles in this group (782 = 6*128+14)

    const char* aSrc  = (const char*)fhat + (size_t)rt * 32768;
    const char* bBase = (const char*)what;

    // ---- prologue: A tile (32KB) -> whole smem, then A -> registers ----
    #pragma unroll
    for (int i = 0; i < 8; i++) {
        int o = wid * 8192 + i * 1024 + lane * 16;
        int s = o ^ (((o >> 8) & 7) << 4);      // source pre-swizzle (involution)
        load_lds16(aSrc + s, smem + o);
    }
    __syncthreads();

    const int lrow = lane & 15;
    const int kgrp = lane >> 4;

    s8v afr[4][2];                        // 8 s8v = 32 VGPR
    #pragma unroll
    for (int kk = 0; kk < 4; kk++)
        #pragma unroll
        for (int m = 0; m < 2; m++) {
            int row = wid * 32 + m * 16 + lrow;
            int b = (row * 256 + kk * 64 + kgrp * 16) ^ ((row & 7) << 4);
            afr[kk][m] = *(const s8v*)(smem + b);
        }
    __syncthreads();                      // afr reads retired before B overwrites

    // ---- stage B(t=0) -> buf0 ----
    {
        const char* src = bBase + (size_t)g * 16384;
        #pragma unroll
        for (int i = 0; i < 4; i++) {
            int o = wid * 4096 + i * 1024 + lane * 16;
            int s = o ^ (((o >> 8) & 7) << 4);
            load_lds16(src + s, smem + o);
        }
    }
    __syncthreads();

    float esum[2][4];
    #pragma unroll
    for (int m = 0; m < 2; m++)
        #pragma unroll
        for (int j = 0; j < 4; j++) esum[m][j] = 0.f;

    int cur = 0;
    for (int t = 0; t < nt; ++t) {
        const int ct = g + 128 * t;
        if (t + 1 < nt) {                 // issue next-tile stage first
            const char* src = bBase + (size_t)(ct + 128) * 16384;
            unsigned char* dstb = smem + (cur ^ 1) * 16384;
            #pragma unroll
            for (int i = 0; i < 4; i++) {
                int o = wid * 4096 + i * 1024 + lane * 16;
                int s = o ^ (((o >> 8) & 7) << 4);
                load_lds16(src + s, dstb + o);
            }
        }

        const unsigned char* bb = smem + cur * 16384;
        f4v acc[2][4];
        f4v zero = {0.f, 0.f, 0.f, 0.f};
        #pragma unroll
        for (int m = 0; m < 2; m++)
            #pragma unroll
            for (int n = 0; n < 4; n++) acc[m][n] = zero;

        #pragma unroll
        for (int kk = 0; kk < 4; kk++) {
            s8v bfr[4];
            #pragma unroll
            for (int n = 0; n < 4; n++) {
                int row = n * 16 + lrow;          // B^T row = output col (0..63)
                int b = (row * 256 + kk * 64 + kgrp * 16) ^ ((row & 7) << 4);
                bfr[n] = *(const s8v*)(bb + b);
            }
            #pragma unroll
            for (int m = 0; m < 2; m++)
                #pragma unroll
                for (int n = 0; n < 4; n++)
                    acc[m][n] = __builtin_amdgcn_mfma_f32_16x16x32_bf16(
                        afr[kk][m], bfr[n], acc[m][n], 0, 0, 0);
        }

        if (ct != NCT64 - 1) {            // fast path: all 64 cols valid
            #pragma unroll
            for (int m = 0; m < 2; m++)
                #pragma unroll
                for (int n = 0; n < 4; n++)
                    #pragma unroll
                    for (int j = 0; j < 4; j++)
                        esum[m][j] += __builtin_amdgcn_exp2f(EXP2_SCALE * acc[m][n][j]);
        } else {                          // tail tile: mask padded cols
            int cbase = ct * 64;
            #pragma unroll
            for (int m = 0; m < 2; m++)
                #pragma unroll
                for (int n = 0; n < 4; n++) {
                    int gc = cbase + n * 16 + lrow;
                    #pragma unroll
                    for (int j = 0; j < 4; j++)
                        if (gc < C_CLS)
                            esum[m][j] += __builtin_amdgcn_exp2f(EXP2_SCALE * acc[m][n][j]);
                }
        }
        __syncthreads();                  // drains stage vmcnt + all bb reads done
        cur ^= 1;
    }

    // ---- epilogue: 16-lane col-reduce, direct write (waves own disjoint rows) ----
    #pragma unroll
    for (int m = 0; m < 2; m++)
        #pragma unroll
        for (int j = 0; j < 4; j++) {
            float v = esum[m][j];
            v += __shfl_xor(v, 1, 64);
            v += __shfl_xor(v, 2, 64);
            v += __shfl_xor(v, 4, 64);
            v += __shfl_xor(v, 8, 64);
            if (lrow == 0) {
                int row = rt * 128 + wid * 32 + m * 16 + kgrp * 4 + j;
                part2[(size_t)row * NG + g] = v;
            }
        }
}

// ---------------------------------------------------------------------------
// One wave per row: S_n = sum of 128 group partials (2 per lane); cos_y via
// fp32 dot of the SAME bf16 normalized vectors; center loss on fp32 inputs.
// rowval[n] = (lse_n - t_n)/N + 0.005 * ||f_n - w_y||^2
// ---------------------------------------------------------------------------
__global__ void finalize_rows_kernel(const float* __restrict__ part2,
                                     const unsigned short* __restrict__ fhat,
                                     const unsigned short* __restrict__ what,
                                     const float* __restrict__ feature,
                                     const float* __restrict__ weight,
                                     const int* __restrict__ label,
                                     float* __restrict__ rowval) {
    int wid = threadIdx.x >> 6, lane = threadIdx.x & 63;
    int n = blockIdx.x * 4 + wid;
    int y = label[n];

    float S = part2[(size_t)n * NG + lane] + part2[(size_t)n * NG + 64 + lane];

    float2 f2 = ((const float2*)feature)[(size_t)n * 64 + lane];
    float2 w2 = ((const float2*)weight)[(size_t)y * 64 + lane];
    float dx = f2.x - w2.x, dy = f2.y - w2.y;
    float cl = dx * dx + dy * dy;

    ushort2 fh = ((const ushort2*)fhat)[(size_t)n * 64 + lane];
    ushort2 wh = ((const ushort2*)what)[(size_t)y * 64 + lane];
    float cy = bf2f(fh.x) * bf2f(wh.x) + bf2f(fh.y) * bf2f(wh.y);

    #pragma unroll
    for (int s = 1; s < 64; s <<= 1) {
        S  += __shfl_xor(S, s, 64);
        cl += __shfl_xor(cl, s, 64);
        cy += __shfl_xor(cy, s, 64);
    }
    if (lane == 0) {
        float t  = S_SCALE * (cy - M_MARGIN);
        float Sp = S - __expf(S_SCALE * cy) + __expf(t);
        rowval[n] = (logf(Sp) - t) * (1.0f / (float)N_ROWS) + 0.005f * cl;
    }
}

__global__ void reduce_final_kernel(const float* __restrict__ rowval, float* __restrict__ out) {
    __shared__ float sbuf[4];
    int t = threadIdx.x;
    float v = rowval[t] + rowval[t + 256] + rowval[t + 512] + rowval[t + 768];
    #pragma unroll
    for (int s = 1; s < 64; s <<= 1) v += __shfl_xor(v, s, 64);
    if ((t & 63) == 0) sbuf[t >> 6] = v;
    __syncthreads();
    if (t == 0) out[0] = sbuf[0] + sbuf[1] + sbuf[2] + sbuf[3];
}

// ---------------------------------------------------------------------------
extern "C" void kernel_launch(void* const* d_in, const int* in_sizes, int n_in,
                              void* d_out, int out_size, void* d_ws, size_t ws_size,
                              hipStream_t stream) {
    const float* feature = (const float*)d_in[0];
    const float* weight  = (const float*)d_in[1];
    const int*   label   = (const int*)d_in[2];

    // Workspace layout (bytes):
    //   what   [0,        12812288)  : 50048*128*2
    //   fhat   [12812288, 13074432)  : 1024*128*2
    //   part2  [13074432, 13598720)  : 1024*128*4
    //   rowval [13598720, 13602816)  : 1024*4
    const size_t WS_NEEDED = 13602816;
    if (ws_size < WS_NEEDED) return;   // defensive: visible failure, not OOB writes

    char* ws = (char*)d_ws;
    unsigned short* what = (unsigned short*)ws;
    unsigned short* fhat = (unsigned short*)(ws + 12812288);
    float*         part2 = (float*)(ws + 13074432);
    float*        rowval = (float*)(ws + 13598720);

    norm_rows_fused<<<dim3((C_PAD + N_ROWS) / 4), 256, 0, stream>>>(weight, feature, what, fhat);
    gemm_exp_kernel<<<dim3(NG, 8), 256, 0, stream>>>((const short*)fhat, (const short*)what, part2);
    finalize_rows_kernel<<<dim3(N_ROWS / 4), 256, 0, stream>>>(part2, fhat, what, feature, weight,
                                                               label, rowval);
    reduce_final_kernel<<<1, 256, 0, stream>>>(rowval, (float*)d_out);
}